// Round 1
// baseline (17.308 us; speedup 1.0000x reference)
//
#include <hip/hip_runtime.h>

// Problem constants (from reference)
#define PS 16           // patch size
#define DR 32           // dst patch rows
#define DC 32           // dst patch cols
#define MULT 2
#define SR (DR * MULT)  // 64
#define SC (DC * MULT)  // 64
#define NB 8            // batch
#define NS 2            // num source images
#define DP (DR * DC)    // 1024 dst patches
#define SP (SR * SC)    // 4096 src patches

// src_images: [NS, NB, 3, SR*PS, SC*PS] f32  -> rows of 1024 floats = 256 float4
// out:        [NB, 3, DR*PS, DC*PS]     f32  -> rows of 512 floats  = 128 float4
//
// One 64-lane wave per (b, j) patch. lane -> (r = lane>>2 in [0,16), q = lane&3),
// each lane copies one float4 per channel c (3 loads + 3 stores).
__global__ __launch_bounds__(256) void MultiViTPatchMapper_kernel(
    const float4* __restrict__ src,
    const int* __restrict__ img_idx,
    const int* __restrict__ sp_idx,
    const int* __restrict__ dp_idx,
    float4* __restrict__ out) {
    const int gpatch = blockIdx.x * 4 + (threadIdx.x >> 6);   // flat (b, j), 0..8191
    const int lane   = threadIdx.x & 63;

    const int b = gpatch >> 10;          // / DP
    // j = gpatch & 1023 (implicit in gpatch indexing of the idx arrays)

    const int img = img_idx[gpatch];
    const int sp  = sp_idx[gpatch];
    const int dp  = dp_idx[gpatch];

    const int sprow = sp >> 6;           // / SC
    const int spcol = sp & 63;           // % SC
    const int dprow = dp >> 5;           // / DC
    const int dpcol = dp & 31;           // % DC

    const int r = lane >> 2;             // patch row 0..15
    const int q = lane & 3;              // float4 within row, 0..3

    // float4 strides
    //   src plane (img,b,c): SR*PS = 1024 rows, each 256 float4
    //   out plane (b,c):     DR*PS = 512 rows,  each 128 float4
    const int src_plane0 = ((img * NB + b) * 3) * (SR * PS);  // row index base
    const int out_plane0 = (b * 3) * (DR * PS);

    const int srow = sprow * PS + r;
    const int drow = dprow * PS + r;
    const int scol = spcol * 4 + q;      // float4 column in src row (256 wide)
    const int dcol = dpcol * 4 + q;      // float4 column in out row (128 wide)

#pragma unroll
    for (int c = 0; c < 3; ++c) {
        const int si = (src_plane0 + c * (SR * PS) + srow) * (SC * PS / 4) + scol;
        const int di = (out_plane0 + c * (DR * PS) + drow) * (DC * PS / 4) + dcol;
        out[di] = src[si];
    }
}

extern "C" void kernel_launch(void* const* d_in, const int* in_sizes, int n_in,
                              void* d_out, int out_size, void* d_ws, size_t ws_size,
                              hipStream_t stream) {
    const float* src     = (const float*)d_in[0];   // [NS, NB, 3, 1024, 1024]
    const int*   img_idx = (const int*)d_in[1];     // [NB, DP]
    const int*   sp_idx  = (const int*)d_in[2];     // [NB, DP]
    const int*   dp_idx  = (const int*)d_in[3];     // [NB, DP]
    float*       out     = (float*)d_out;           // [NB, 3, 512, 512]

    const int total_patches = NB * DP;              // 8192
    const int blocks = total_patches / 4;           // 2048 blocks x 256 threads (4 waves)

    MultiViTPatchMapper_kernel<<<blocks, 256, 0, stream>>>(
        (const float4*)src, img_idx, sp_idx, dp_idx, (float4*)out);
}